// Round 1
// baseline (819.100 us; speedup 1.0000x reference)
//
#include <hip/hip_runtime.h>
#include <hip/hip_bf16.h>
#include <cstdint>

// B=64, S=2048, H=512
// in: dec[64,512] f32, enc[64,2048,512] f32, Wq[512,512] f32, Wk[512,512] f32, v[512] f32
// out: context[64,512] ++ weights[64,2048]  (163840 f32)
// ws: [0,512K) Wk bf16; [512K,640K) q f32

typedef __attribute__((ext_vector_type(8))) short short8;
typedef __attribute__((ext_vector_type(4))) float f32x4;

__device__ __forceinline__ unsigned short f2bf(float f) {
    unsigned u = __builtin_bit_cast(unsigned, f);
    u += 0x7FFFu + ((u >> 16) & 1u);       // RNE; inputs are normal floats
    return (unsigned short)(u >> 16);
}

__device__ __forceinline__ float tanh_fast(float x) {
    // tanh(x) = 1 - 2/(exp(2x)+1); exp overflow -> inf -> rcp -> 0 -> +1 (correct limit)
    float e = __expf(2.0f * x);
    return 1.0f - 2.0f * __builtin_amdgcn_rcpf(e + 1.0f);
}

// ---------------- kernel 1: cast W_k to bf16 ----------------
__global__ void cast_wk_kernel(const float* __restrict__ wk, unsigned short* __restrict__ wkb) {
    int i = (blockIdx.x * 256 + threadIdx.x) * 4;          // 256 blocks x 256 thr x 4 = 262144
    float4 f = *(const float4*)(wk + i);
    ushort4 o;
    o.x = f2bf(f.x); o.y = f2bf(f.y); o.z = f2bf(f.z); o.w = f2bf(f.w);
    *(ushort4*)(wkb + i) = o;
}

// ---------------- kernel 2: q = dec @ Wq^T ----------------
__global__ void q_kernel(const float* __restrict__ dec, const float* __restrict__ wq,
                         float* __restrict__ q) {
    int b  = blockIdx.x >> 3;
    int g0 = (blockIdx.x & 7) * 64;
    int t = threadIdx.x, lane = t & 63, w = t >> 6;
    __shared__ float dls[512];
    dls[t] = dec[b * 512 + t];
    dls[t + 256] = dec[b * 512 + 256 + t];
    __syncthreads();
    #pragma unroll
    for (int gi = 0; gi < 16; ++gi) {
        int g = g0 + w + gi * 4;
        float acc = 0.f;
        #pragma unroll
        for (int it = 0; it < 2; ++it) {
            int h = (it * 64 + lane) * 4;                  // wave reads 1KiB contiguous of row g
            float4 wv = *(const float4*)(wq + (size_t)g * 512 + h);
            acc += wv.x * dls[h] + wv.y * dls[h + 1] + wv.z * dls[h + 2] + wv.w * dls[h + 3];
        }
        #pragma unroll
        for (int m = 32; m; m >>= 1) acc += __shfl_xor(acc, m, 64);
        if (lane == 0) q[b * 512 + g] = acc;
    }
}

// ---------------- kernel 3: fused keys-GEMM + tanh·v row-reduce -> raw scores ----------------
// grid: 2048 wg (one per 64-row tile of M=B*S), 256 thr.
// wg tile: 64 rows x N=512 (full) x K=512, BK=32. wave w covers cols [128w,128w+128).
__launch_bounds__(256, 2)
__global__ void scores_kernel(const float* __restrict__ enc, const unsigned short* __restrict__ wkb,
                              const float* __restrict__ q, const float* __restrict__ v,
                              float* __restrict__ scores) {
    __shared__ short As[64 * 40];       // 80B row stride: uniform 2-way banks (free)
    __shared__ short Bs[512 * 40];
    __shared__ float q_s[512];
    __shared__ float v_s[512];
    __shared__ float red[4][64];

    int t = threadIdx.x, lane = t & 63, w = t >> 6;
    int quad = lane >> 4, l15 = lane & 15;
    int tile = blockIdx.x;
    int b = tile >> 5;                   // 32 tiles per batch
    size_t m0 = (size_t)tile * 64;

    q_s[t] = q[b * 512 + t];   q_s[t + 256] = q[b * 512 + 256 + t];
    v_s[t] = v[t];             v_s[t + 256] = v[t + 256];

    f32x4 acc[4][8];
    #pragma unroll
    for (int i = 0; i < 4; ++i)
        #pragma unroll
        for (int j = 0; j < 8; ++j)
            acc[i][j] = (f32x4){0.f, 0.f, 0.f, 0.f};

    int arow = t >> 2, akq = t & 3;                       // A stage: 64 rows x 32k
    const float* aptr = enc + (m0 + arow) * 512 + akq * 8;
    int brow = t >> 2, bkq = t & 3;                       // B stage: 512 rows x 32k

    for (int kk = 0; kk < 512; kk += 32) {
        // global prefetch into regs (before barrier)
        float4 fa0 = *(const float4*)(aptr + kk);
        float4 fa1 = *(const float4*)(aptr + kk + 4);
        int4 bv[8];
        #pragma unroll
        for (int i = 0; i < 8; ++i)
            bv[i] = *(const int4*)(wkb + (size_t)(brow + i * 64) * 512 + kk + bkq * 8);

        __syncthreads();                                  // prev iter frag reads done
        short8 av;
        av[0] = (short)f2bf(fa0.x); av[1] = (short)f2bf(fa0.y);
        av[2] = (short)f2bf(fa0.z); av[3] = (short)f2bf(fa0.w);
        av[4] = (short)f2bf(fa1.x); av[5] = (short)f2bf(fa1.y);
        av[6] = (short)f2bf(fa1.z); av[7] = (short)f2bf(fa1.w);
        *(short8*)&As[arow * 40 + akq * 8] = av;
        #pragma unroll
        for (int i = 0; i < 8; ++i)
            *(int4*)&Bs[(brow + i * 64) * 40 + bkq * 8] = bv[i];
        __syncthreads();

        short8 af[4];
        #pragma unroll
        for (int mt = 0; mt < 4; ++mt)
            af[mt] = *(short8*)&As[(mt * 16 + l15) * 40 + quad * 8];
        #pragma unroll
        for (int nt = 0; nt < 8; ++nt) {
            short8 bf = *(short8*)&Bs[(w * 128 + nt * 16 + l15) * 40 + quad * 8];
            #pragma unroll
            for (int mt = 0; mt < 4; ++mt)
                acc[mt][nt] = __builtin_amdgcn_mfma_f32_16x16x32_bf16(af[mt], bf, acc[mt][nt], 0, 0, 0);
        }
    }

    // epilogue: rs[mt][r] = sum over wave's 128 cols of tanh(q+keys)*v
    // C/D layout: col = l15, row(in 16-tile) = quad*4 + r   [m89/m91]
    float rs[4][4];
    #pragma unroll
    for (int mt = 0; mt < 4; ++mt)
        #pragma unroll
        for (int r = 0; r < 4; ++r) rs[mt][r] = 0.f;
    #pragma unroll
    for (int nt = 0; nt < 8; ++nt) {
        int g = w * 128 + nt * 16 + l15;
        float qb = q_s[g], vv = v_s[g];
        #pragma unroll
        for (int mt = 0; mt < 4; ++mt)
            #pragma unroll
            for (int r = 0; r < 4; ++r)
                rs[mt][r] += tanh_fast(qb + acc[mt][nt][r]) * vv;
    }
    #pragma unroll
    for (int m = 1; m <= 8; m <<= 1)
        #pragma unroll
        for (int mt = 0; mt < 4; ++mt)
            #pragma unroll
            for (int r = 0; r < 4; ++r)
                rs[mt][r] += __shfl_xor(rs[mt][r], m, 64);
    if (l15 == 0) {
        #pragma unroll
        for (int mt = 0; mt < 4; ++mt)
            #pragma unroll
            for (int r = 0; r < 4; ++r)
                red[w][mt * 16 + quad * 4 + r] = rs[mt][r];
    }
    __syncthreads();
    if (t < 64) {
        float sc = red[0][t] + red[1][t] + red[2][t] + red[3][t];
        scores[m0 + t] = sc;                               // linear b*2048 + s
    }
}

// ---------------- kernel 4: softmax in place + zero context region ----------------
__global__ void softmax_kernel(float* __restrict__ out) {
    int b = blockIdx.x, t = threadIdx.x, lane = t & 63, w = t >> 6;
    float* sc = out + 32768 + b * 2048;
    __shared__ float wred[4];
    float vals[8];
    float mx = -1e30f;
    #pragma unroll
    for (int i = 0; i < 8; ++i) { vals[i] = sc[t + i * 256]; mx = fmaxf(mx, vals[i]); }
    #pragma unroll
    for (int m = 32; m; m >>= 1) mx = fmaxf(mx, __shfl_xor(mx, m, 64));
    if (lane == 0) wred[w] = mx;
    __syncthreads();
    mx = fmaxf(fmaxf(wred[0], wred[1]), fmaxf(wred[2], wred[3]));
    __syncthreads();
    float s = 0.f;
    #pragma unroll
    for (int i = 0; i < 8; ++i) { vals[i] = __expf(vals[i] - mx); s += vals[i]; }
    #pragma unroll
    for (int m = 32; m; m >>= 1) s += __shfl_xor(s, m, 64);
    if (lane == 0) wred[w] = s;
    __syncthreads();
    s = wred[0] + wred[1] + wred[2] + wred[3];
    float inv = 1.0f / s;
    #pragma unroll
    for (int i = 0; i < 8; ++i) sc[t + i * 256] = vals[i] * inv;
    // zero context region for this batch (d_out is poisoned before each launch)
    out[b * 512 + t] = 0.f;
    out[b * 512 + 256 + t] = 0.f;
}

// ---------------- kernel 5: context = sum_s w * enc ----------------
__launch_bounds__(256)
__global__ void context_kernel(const float* __restrict__ enc, float* __restrict__ out) {
    int blk = blockIdx.x;                                  // 512 = 64b x 2hc x 4ss
    int b = blk >> 3, rem = blk & 7, hc = rem >> 2, ss = rem & 3;
    int t = threadIdx.x, lane = t & 63, sg = t >> 6;
    int h = hc * 256 + lane * 4;
    const float* wptr = out + 32768 + b * 2048;
    float ax = 0.f, ay = 0.f, az = 0.f, aw = 0.f;
    int sbase = ss * 512 + sg;
    #pragma unroll 4
    for (int i = 0; i < 128; ++i) {
        int s = sbase + i * 4;
        float wv = wptr[s];                                // wave-uniform -> scalar load
        float4 e = *(const float4*)(enc + ((size_t)b * 2048 + s) * 512 + h);
        ax += wv * e.x; ay += wv * e.y; az += wv * e.z; aw += wv * e.w;
    }
    __shared__ float red[4][64][4];
    red[sg][lane][0] = ax; red[sg][lane][1] = ay; red[sg][lane][2] = az; red[sg][lane][3] = aw;
    __syncthreads();
    if (t < 64) {
        float* dst = out + b * 512 + hc * 256 + t * 4;
        #pragma unroll
        for (int j = 0; j < 4; ++j) {
            float sv = red[0][t][j] + red[1][t][j] + red[2][t][j] + red[3][t][j];
            atomicAdd(dst + j, sv);
        }
    }
}

extern "C" void kernel_launch(void* const* d_in, const int* in_sizes, int n_in,
                              void* d_out, int out_size, void* d_ws, size_t ws_size,
                              hipStream_t stream) {
    const float* dec = (const float*)d_in[0];
    const float* enc = (const float*)d_in[1];
    const float* wq  = (const float*)d_in[2];
    const float* wk  = (const float*)d_in[3];
    const float* v   = (const float*)d_in[4];
    float* out = (float*)d_out;

    unsigned short* wkb = (unsigned short*)d_ws;                 // 512*512*2 = 512 KiB
    float* q = (float*)((char*)d_ws + 512 * 512 * 2);            // 64*512*4  = 128 KiB

    cast_wk_kernel<<<256, 256, 0, stream>>>(wk, wkb);
    q_kernel<<<512, 256, 0, stream>>>(dec, wq, q);
    scores_kernel<<<2048, 256, 0, stream>>>(enc, wkb, q, v, out + 32768);
    softmax_kernel<<<64, 256, 0, stream>>>(out);
    context_kernel<<<512, 256, 0, stream>>>(enc, out);
}

// Round 2
// 468.989 us; speedup vs baseline: 1.7465x; 1.7465x over previous
//
#include <hip/hip_runtime.h>
#include <hip/hip_bf16.h>
#include <cstdint>

// B=64, S=2048, H=512
// in: dec[64,512] f32, enc[64,2048,512] f32, Wq[512,512] f32, Wk[512,512] f32, v[512] f32
// out: context[64,512] ++ weights[64,2048]  (163840 f32)
// ws: [0,512K) Wk bf16; [512K,640K) q f32

typedef __attribute__((ext_vector_type(8))) short short8;
typedef __attribute__((ext_vector_type(4))) float f32x4;

__device__ __forceinline__ unsigned short f2bf(float f) {
    unsigned u = __builtin_bit_cast(unsigned, f);
    u += 0x7FFFu + ((u >> 16) & 1u);       // RNE; inputs are normal floats
    return (unsigned short)(u >> 16);
}

__device__ __forceinline__ float tanh_fast(float x) {
    // tanh(x) = 1 - 2/(exp(2x)+1); exp overflow -> inf -> rcp -> 0 -> +1 (correct limit)
    float e = __expf(2.0f * x);
    return 1.0f - 2.0f * __builtin_amdgcn_rcpf(e + 1.0f);
}

// async global->LDS, 16B per lane; dest must be wave-uniform base + lane*16
__device__ __forceinline__ void async16(const unsigned short* g, short* l) {
    __builtin_amdgcn_global_load_lds(
        (const __attribute__((address_space(1))) unsigned int*)g,
        (__attribute__((address_space(3))) unsigned int*)l, 16, 0, 0);
}

// ---------------- kernel 1: cast W_k to bf16 ----------------
__global__ void cast_wk_kernel(const float* __restrict__ wk, unsigned short* __restrict__ wkb) {
    int i = (blockIdx.x * 256 + threadIdx.x) * 4;          // 256 blocks x 256 thr x 4 = 262144
    float4 f = *(const float4*)(wk + i);
    ushort4 o;
    o.x = f2bf(f.x); o.y = f2bf(f.y); o.z = f2bf(f.z); o.w = f2bf(f.w);
    *(ushort4*)(wkb + i) = o;
}

// ---------------- kernel 2: q = dec @ Wq^T ----------------
__global__ void q_kernel(const float* __restrict__ dec, const float* __restrict__ wq,
                         float* __restrict__ q) {
    int b  = blockIdx.x >> 3;
    int g0 = (blockIdx.x & 7) * 64;
    int t = threadIdx.x, lane = t & 63, w = t >> 6;
    __shared__ float dls[512];
    dls[t] = dec[b * 512 + t];
    dls[t + 256] = dec[b * 512 + 256 + t];
    __syncthreads();
    #pragma unroll
    for (int gi = 0; gi < 16; ++gi) {
        int g = g0 + w + gi * 4;
        float acc = 0.f;
        #pragma unroll
        for (int it = 0; it < 2; ++it) {
            int h = (it * 64 + lane) * 4;                  // wave reads 1KiB contiguous of row g
            float4 wv = *(const float4*)(wq + (size_t)g * 512 + h);
            acc += wv.x * dls[h] + wv.y * dls[h + 1] + wv.z * dls[h + 2] + wv.w * dls[h + 3];
        }
        #pragma unroll
        for (int m = 32; m; m >>= 1) acc += __shfl_xor(acc, m, 64);
        if (lane == 0) q[b * 512 + g] = acc;
    }
}

// ---------------- kernel 3: fused keys-GEMM + tanh·v row-reduce -> raw scores ----------------
// grid: 2048 wg (one per 64-row tile of M=B*S), 256 thr.
// wg tile: 64 rows x N=512 (full) x K=512, BK=32. wave w covers cols [128w,128w+128).
// B staged via global_load_lds (zero staging VGPRs — R0's bv[8] spilled 941 MB to scratch).
// Bs unpadded [512][32] bf16 with XOR chunk swizzle (phys_chunk = kq ^ ((row>>1)&3))
// -> frag ds_read_b128 hits all 8 bank-groups across 16 rows: 2-way, free (m136).
__launch_bounds__(256, 2)
__global__ void scores_kernel(const float* __restrict__ enc, const unsigned short* __restrict__ wkb,
                              const float* __restrict__ q, const float* __restrict__ v,
                              float* __restrict__ scores) {
    __shared__ __align__(16) short Bs[512 * 32];   // 32 KiB, layout forced by global_load_lds
    __shared__ __align__(16) short As[64 * 40];    // 80B row stride: all 8 bank-groups (free)
    __shared__ float q_s[512];
    __shared__ float v_s[512];
    __shared__ float red[4][64];

    int t = threadIdx.x, lane = t & 63, w = t >> 6;
    int quad = lane >> 4, l15 = lane & 15;
    int tile = blockIdx.x;
    int b = tile >> 5;                   // 32 tiles per batch
    size_t m0 = (size_t)tile * 64;

    q_s[t] = q[b * 512 + t];   q_s[t + 256] = q[b * 512 + 256 + t];
    v_s[t] = v[t];             v_s[t + 256] = v[t + 256];

    f32x4 acc[4][8];
    #pragma unroll
    for (int i = 0; i < 4; ++i)
        #pragma unroll
        for (int j = 0; j < 8; ++j)
            acc[i][j] = (f32x4){0.f, 0.f, 0.f, 0.f};

    // A stage mapping: thread t -> row t>>2, k-chunk t&3 (8 floats)
    int arow = t >> 2, akq = t & 3;
    const float* aptr = enc + (m0 + arow) * 512 + akq * 8;

    // B stage mapping (async): wave w, pass i covers rows i*64+w*16 .. +16.
    // lane -> row_phys = +(lane>>2), phys chunk = lane&3; logical k-chunk is swizzled:
    int kqs = (lane & 3) ^ ((lane >> 3) & 3);            // == (lane&3) ^ ((row_phys>>1)&3)
    const unsigned short* bgbase = wkb + (size_t)(w * 16 + (lane >> 2)) * 512 + kqs * 8;
    short* blbase = &Bs[(w * 16 + (lane >> 2)) * 32 + (lane & 3) * 8];  // base + lane*16

    for (int kk = 0; kk < 512; kk += 32) {
        __syncthreads();                                 // prev iter frag reads done
        #pragma unroll
        for (int i = 0; i < 8; ++i)
            async16(bgbase + (size_t)i * 64 * 512 + kk, blbase + i * 64 * 32);
        float4 fa0 = *(const float4*)(aptr + kk);
        float4 fa1 = *(const float4*)(aptr + kk + 4);
        short8 av;
        av[0] = (short)f2bf(fa0.x); av[1] = (short)f2bf(fa0.y);
        av[2] = (short)f2bf(fa0.z); av[3] = (short)f2bf(fa0.w);
        av[4] = (short)f2bf(fa1.x); av[5] = (short)f2bf(fa1.y);
        av[6] = (short)f2bf(fa1.z); av[7] = (short)f2bf(fa1.w);
        *(short8*)&As[arow * 40 + akq * 8] = av;
        __syncthreads();                                 // drains vmcnt (global_load_lds) + lds

        short8 af[4];
        #pragma unroll
        for (int mt = 0; mt < 4; ++mt)
            af[mt] = *(short8*)&As[(mt * 16 + l15) * 40 + quad * 8];
        #pragma unroll
        for (int nt = 0; nt < 8; ++nt) {
            int brow = w * 128 + nt * 16 + l15;
            short8 bf = *(short8*)&Bs[brow * 32 + (quad ^ ((l15 >> 1) & 3)) * 8];
            #pragma unroll
            for (int mt = 0; mt < 4; ++mt)
                acc[mt][nt] = __builtin_amdgcn_mfma_f32_16x16x32_bf16(af[mt], bf, acc[mt][nt], 0, 0, 0);
        }
    }

    // epilogue: rs[mt][r] = sum over wave's 128 cols of tanh(q+keys)*v
    // C/D layout: col = l15, row(in 16-tile) = quad*4 + r   [m89/m91]
    float rs[4][4];
    #pragma unroll
    for (int mt = 0; mt < 4; ++mt)
        #pragma unroll
        for (int r = 0; r < 4; ++r) rs[mt][r] = 0.f;
    #pragma unroll
    for (int nt = 0; nt < 8; ++nt) {
        int g = w * 128 + nt * 16 + l15;
        float qb = q_s[g], vv = v_s[g];
        #pragma unroll
        for (int mt = 0; mt < 4; ++mt)
            #pragma unroll
            for (int r = 0; r < 4; ++r)
                rs[mt][r] += tanh_fast(qb + acc[mt][nt][r]) * vv;
    }
    #pragma unroll
    for (int m = 1; m <= 8; m <<= 1)
        #pragma unroll
        for (int mt = 0; mt < 4; ++mt)
            #pragma unroll
            for (int r = 0; r < 4; ++r)
                rs[mt][r] += __shfl_xor(rs[mt][r], m, 64);
    if (l15 == 0) {
        #pragma unroll
        for (int mt = 0; mt < 4; ++mt)
            #pragma unroll
            for (int r = 0; r < 4; ++r)
                red[w][mt * 16 + quad * 4 + r] = rs[mt][r];
    }
    __syncthreads();
    if (t < 64) {
        float sc = red[0][t] + red[1][t] + red[2][t] + red[3][t];
        scores[m0 + t] = sc;                               // linear b*2048 + s
    }
}

// ---------------- kernel 4: softmax in place + zero context region ----------------
__global__ void softmax_kernel(float* __restrict__ out) {
    int b = blockIdx.x, t = threadIdx.x, lane = t & 63, w = t >> 6;
    float* sc = out + 32768 + b * 2048;
    __shared__ float wred[4];
    float vals[8];
    float mx = -1e30f;
    #pragma unroll
    for (int i = 0; i < 8; ++i) { vals[i] = sc[t + i * 256]; mx = fmaxf(mx, vals[i]); }
    #pragma unroll
    for (int m = 32; m; m >>= 1) mx = fmaxf(mx, __shfl_xor(mx, m, 64));
    if (lane == 0) wred[w] = mx;
    __syncthreads();
    mx = fmaxf(fmaxf(wred[0], wred[1]), fmaxf(wred[2], wred[3]));
    __syncthreads();
    float s = 0.f;
    #pragma unroll
    for (int i = 0; i < 8; ++i) { vals[i] = __expf(vals[i] - mx); s += vals[i]; }
    #pragma unroll
    for (int m = 32; m; m >>= 1) s += __shfl_xor(s, m, 64);
    if (lane == 0) wred[w] = s;
    __syncthreads();
    s = wred[0] + wred[1] + wred[2] + wred[3];
    float inv = 1.0f / s;
    #pragma unroll
    for (int i = 0; i < 8; ++i) sc[t + i * 256] = vals[i] * inv;
    // zero context region for this batch (d_out is poisoned before each launch)
    out[b * 512 + t] = 0.f;
    out[b * 512 + 256 + t] = 0.f;
}

// ---------------- kernel 5: context = sum_s w * enc ----------------
__launch_bounds__(256)
__global__ void context_kernel(const float* __restrict__ enc, float* __restrict__ out) {
    int blk = blockIdx.x;                                  // 512 = 64b x 2hc x 4ss
    int b = blk >> 3, rem = blk & 7, hc = rem >> 2, ss = rem & 3;
    int t = threadIdx.x, lane = t & 63, sg = t >> 6;
    int h = hc * 256 + lane * 4;
    const float* wptr = out + 32768 + b * 2048;
    float ax = 0.f, ay = 0.f, az = 0.f, aw = 0.f;
    int sbase = ss * 512 + sg;
    #pragma unroll 4
    for (int i = 0; i < 128; ++i) {
        int s = sbase + i * 4;
        float wv = wptr[s];                                // wave-uniform -> scalar load
        float4 e = *(const float4*)(enc + ((size_t)b * 2048 + s) * 512 + h);
        ax += wv * e.x; ay += wv * e.y; az += wv * e.z; aw += wv * e.w;
    }
    __shared__ float red[4][64][4];
    red[sg][lane][0] = ax; red[sg][lane][1] = ay; red[sg][lane][2] = az; red[sg][lane][3] = aw;
    __syncthreads();
    if (t < 64) {
        float* dst = out + b * 512 + hc * 256 + t * 4;
        #pragma unroll
        for (int j = 0; j < 4; ++j) {
            float sv = red[0][t][j] + red[1][t][j] + red[2][t][j] + red[3][t][j];
            atomicAdd(dst + j, sv);
        }
    }
}

extern "C" void kernel_launch(void* const* d_in, const int* in_sizes, int n_in,
                              void* d_out, int out_size, void* d_ws, size_t ws_size,
                              hipStream_t stream) {
    const float* dec = (const float*)d_in[0];
    const float* enc = (const float*)d_in[1];
    const float* wq  = (const float*)d_in[2];
    const float* wk  = (const float*)d_in[3];
    const float* v   = (const float*)d_in[4];
    float* out = (float*)d_out;

    unsigned short* wkb = (unsigned short*)d_ws;                 // 512*512*2 = 512 KiB
    float* q = (float*)((char*)d_ws + 512 * 512 * 2);            // 64*512*4  = 128 KiB

    cast_wk_kernel<<<256, 256, 0, stream>>>(wk, wkb);
    q_kernel<<<512, 256, 0, stream>>>(dec, wq, q);
    scores_kernel<<<2048, 256, 0, stream>>>(enc, wkb, q, v, out + 32768);
    softmax_kernel<<<64, 256, 0, stream>>>(out);
    context_kernel<<<512, 256, 0, stream>>>(enc, out);
}

// Round 3
// 468.608 us; speedup vs baseline: 1.7479x; 1.0008x over previous
//
#include <hip/hip_runtime.h>
#include <hip/hip_bf16.h>
#include <cstdint>

// B=64, S=2048, H=512
// in: dec[64,512] f32, enc[64,2048,512] f32, Wq[512,512] f32, Wk[512,512] f32, v[512] f32
// out: context[64,512] ++ weights[64,2048]  (163840 f32)
// ws: [0,512K) Wk bf16; [512K,640K) q f32

typedef __attribute__((ext_vector_type(8))) short short8;
typedef __attribute__((ext_vector_type(4))) float f32x4;

__device__ __forceinline__ unsigned short f2bf(float f) {
    unsigned u = __builtin_bit_cast(unsigned, f);
    u += 0x7FFFu + ((u >> 16) & 1u);       // RNE; inputs are normal floats
    return (unsigned short)(u >> 16);
}

__device__ __forceinline__ float tanh_fast(float x) {
    // tanh(x) = 1 - 2/(exp(2x)+1); exp overflow -> inf -> rcp -> 0 -> +1 (correct limit)
    float e = __expf(2.0f * x);
    return 1.0f - 2.0f * __builtin_amdgcn_rcpf(e + 1.0f);
}

// async global->LDS, 16B per lane; dest must be wave-uniform base + lane*16
__device__ __forceinline__ void async16(const unsigned short* g, short* l) {
    __builtin_amdgcn_global_load_lds(
        (const __attribute__((address_space(1))) unsigned int*)g,
        (__attribute__((address_space(3))) unsigned int*)l, 16, 0, 0);
}

// ---------------- kernel 1: cast W_k to bf16 ----------------
__global__ void cast_wk_kernel(const float* __restrict__ wk, unsigned short* __restrict__ wkb) {
    int i = (blockIdx.x * 256 + threadIdx.x) * 4;          // 256 blocks x 256 thr x 4 = 262144
    float4 f = *(const float4*)(wk + i);
    ushort4 o;
    o.x = f2bf(f.x); o.y = f2bf(f.y); o.z = f2bf(f.z); o.w = f2bf(f.w);
    *(ushort4*)(wkb + i) = o;
}

// ---------------- kernel 2: q = dec @ Wq^T ----------------
__global__ void q_kernel(const float* __restrict__ dec, const float* __restrict__ wq,
                         float* __restrict__ q) {
    int b  = blockIdx.x >> 3;
    int g0 = (blockIdx.x & 7) * 64;
    int t = threadIdx.x, lane = t & 63, w = t >> 6;
    __shared__ float dls[512];
    dls[t] = dec[b * 512 + t];
    dls[t + 256] = dec[b * 512 + 256 + t];
    __syncthreads();
    #pragma unroll
    for (int gi = 0; gi < 16; ++gi) {
        int g = g0 + w + gi * 4;
        float acc = 0.f;
        #pragma unroll
        for (int it = 0; it < 2; ++it) {
            int h = (it * 64 + lane) * 4;                  // wave reads 1KiB contiguous of row g
            float4 wv = *(const float4*)(wq + (size_t)g * 512 + h);
            acc += wv.x * dls[h] + wv.y * dls[h + 1] + wv.z * dls[h + 2] + wv.w * dls[h + 3];
        }
        #pragma unroll
        for (int m = 32; m; m >>= 1) acc += __shfl_xor(acc, m, 64);
        if (lane == 0) q[b * 512 + g] = acc;
    }
}

// ---------------- kernel 3: fused keys-GEMM + tanh·v row-reduce -> raw scores ----------------
// grid: 2048 wg (one per 64-row tile of M=B*S), 256 thr.
// wg tile: 64 rows x N=512 (full) x K=512, BK=32. wave w covers cols [128w,128w+128).
// B staged via global_load_lds (zero staging VGPRs — R0's bv[8] spilled 941 MB to scratch).
// Bs unpadded [512][32] bf16 with XOR chunk swizzle (phys_chunk = kq ^ ((row>>1)&3))
// -> frag ds_read_b128 hits all 8 bank-groups across 16 rows: 2-way, free (m136).
__launch_bounds__(256, 2)
__global__ void scores_kernel(const float* __restrict__ enc, const unsigned short* __restrict__ wkb,
                              const float* __restrict__ q, const float* __restrict__ v,
                              float* __restrict__ scores) {
    __shared__ __align__(16) short Bs[512 * 32];   // 32 KiB, layout forced by global_load_lds
    __shared__ __align__(16) short As[64 * 40];    // 80B row stride: all 8 bank-groups (free)
    __shared__ float q_s[512];
    __shared__ float v_s[512];
    __shared__ float red[4][64];

    int t = threadIdx.x, lane = t & 63, w = t >> 6;
    int quad = lane >> 4, l15 = lane & 15;
    int tile = blockIdx.x;
    int b = tile >> 5;                   // 32 tiles per batch
    size_t m0 = (size_t)tile * 64;

    q_s[t] = q[b * 512 + t];   q_s[t + 256] = q[b * 512 + 256 + t];
    v_s[t] = v[t];             v_s[t + 256] = v[t + 256];

    f32x4 acc[4][8];
    #pragma unroll
    for (int i = 0; i < 4; ++i)
        #pragma unroll
        for (int j = 0; j < 8; ++j)
            acc[i][j] = (f32x4){0.f, 0.f, 0.f, 0.f};

    // A stage mapping: thread t -> row t>>2, k-chunk t&3 (8 floats)
    int arow = t >> 2, akq = t & 3;
    const float* aptr = enc + (m0 + arow) * 512 + akq * 8;

    // B stage mapping (async): wave w, pass i covers rows i*64+w*16 .. +16.
    // lane -> row_phys = +(lane>>2), phys chunk = lane&3; logical k-chunk is swizzled:
    int kqs = (lane & 3) ^ ((lane >> 3) & 3);            // == (lane&3) ^ ((row_phys>>1)&3)
    const unsigned short* bgbase = wkb + (size_t)(w * 16 + (lane >> 2)) * 512 + kqs * 8;
    short* blbase = &Bs[(w * 16 + (lane >> 2)) * 32 + (lane & 3) * 8];  // base + lane*16

    for (int kk = 0; kk < 512; kk += 32) {
        __syncthreads();                                 // prev iter frag reads done
        #pragma unroll
        for (int i = 0; i < 8; ++i)
            async16(bgbase + (size_t)i * 64 * 512 + kk, blbase + i * 64 * 32);
        float4 fa0 = *(const float4*)(aptr + kk);
        float4 fa1 = *(const float4*)(aptr + kk + 4);
        short8 av;
        av[0] = (short)f2bf(fa0.x); av[1] = (short)f2bf(fa0.y);
        av[2] = (short)f2bf(fa0.z); av[3] = (short)f2bf(fa0.w);
        av[4] = (short)f2bf(fa1.x); av[5] = (short)f2bf(fa1.y);
        av[6] = (short)f2bf(fa1.z); av[7] = (short)f2bf(fa1.w);
        *(short8*)&As[arow * 40 + akq * 8] = av;
        __syncthreads();                                 // drains vmcnt (global_load_lds) + lds

        short8 af[4];
        #pragma unroll
        for (int mt = 0; mt < 4; ++mt)
            af[mt] = *(short8*)&As[(mt * 16 + l15) * 40 + quad * 8];
        #pragma unroll
        for (int nt = 0; nt < 8; ++nt) {
            int brow = w * 128 + nt * 16 + l15;
            short8 bf = *(short8*)&Bs[brow * 32 + (quad ^ ((l15 >> 1) & 3)) * 8];
            #pragma unroll
            for (int mt = 0; mt < 4; ++mt)
                acc[mt][nt] = __builtin_amdgcn_mfma_f32_16x16x32_bf16(af[mt], bf, acc[mt][nt], 0, 0, 0);
        }
    }

    // epilogue: rs[mt][r] = sum over wave's 128 cols of tanh(q+keys)*v
    // C/D layout: col = l15, row(in 16-tile) = quad*4 + r   [m89/m91]
    float rs[4][4];
    #pragma unroll
    for (int mt = 0; mt < 4; ++mt)
        #pragma unroll
        for (int r = 0; r < 4; ++r) rs[mt][r] = 0.f;
    #pragma unroll
    for (int nt = 0; nt < 8; ++nt) {
        int g = w * 128 + nt * 16 + l15;
        float qb = q_s[g], vv = v_s[g];
        #pragma unroll
        for (int mt = 0; mt < 4; ++mt)
            #pragma unroll
            for (int r = 0; r < 4; ++r)
                rs[mt][r] += tanh_fast(qb + acc[mt][nt][r]) * vv;
    }
    #pragma unroll
    for (int m = 1; m <= 8; m <<= 1)
        #pragma unroll
        for (int mt = 0; mt < 4; ++mt)
            #pragma unroll
            for (int r = 0; r < 4; ++r)
                rs[mt][r] += __shfl_xor(rs[mt][r], m, 64);
    if (l15 == 0) {
        #pragma unroll
        for (int mt = 0; mt < 4; ++mt)
            #pragma unroll
            for (int r = 0; r < 4; ++r)
                red[w][mt * 16 + quad * 4 + r] = rs[mt][r];
    }
    __syncthreads();
    if (t < 64) {
        float sc = red[0][t] + red[1][t] + red[2][t] + red[3][t];
        scores[m0 + t] = sc;                               // linear b*2048 + s
    }
}

// ---------------- kernel 4: softmax in place + zero context region ----------------
__global__ void softmax_kernel(float* __restrict__ out) {
    int b = blockIdx.x, t = threadIdx.x, lane = t & 63, w = t >> 6;
    float* sc = out + 32768 + b * 2048;
    __shared__ float wred[4];
    float vals[8];
    float mx = -1e30f;
    #pragma unroll
    for (int i = 0; i < 8; ++i) { vals[i] = sc[t + i * 256]; mx = fmaxf(mx, vals[i]); }
    #pragma unroll
    for (int m = 32; m; m >>= 1) mx = fmaxf(mx, __shfl_xor(mx, m, 64));
    if (lane == 0) wred[w] = mx;
    __syncthreads();
    mx = fmaxf(fmaxf(wred[0], wred[1]), fmaxf(wred[2], wred[3]));
    __syncthreads();
    float s = 0.f;
    #pragma unroll
    for (int i = 0; i < 8; ++i) { vals[i] = __expf(vals[i] - mx); s += vals[i]; }
    #pragma unroll
    for (int m = 32; m; m >>= 1) s += __shfl_xor(s, m, 64);
    if (lane == 0) wred[w] = s;
    __syncthreads();
    s = wred[0] + wred[1] + wred[2] + wred[3];
    float inv = 1.0f / s;
    #pragma unroll
    for (int i = 0; i < 8; ++i) sc[t + i * 256] = vals[i] * inv;
    // zero context region for this batch (d_out is poisoned before each launch)
    out[b * 512 + t] = 0.f;
    out[b * 512 + 256 + t] = 0.f;
}

// ---------------- kernel 5: context = sum_s w * enc ----------------
// grid 2048 = 64b x 2hc x 16ss (8 blocks/CU, 32 waves/CU — R2 was 512 blocks = 2/CU,
// latency-bound at ~1.7 TB/s). Each block: 128 s-rows, 32 iters/wave, unroll 8
// -> 8 x 1KiB wave-loads in flight. 16 atomic partials per output element.
__launch_bounds__(256)
__global__ void context_kernel(const float* __restrict__ enc, float* __restrict__ out) {
    int blk = blockIdx.x;
    int b = blk >> 5, rem = blk & 31, hc = rem >> 4, ss = rem & 15;
    int t = threadIdx.x, lane = t & 63, sg = t >> 6;
    int h = hc * 256 + lane * 4;
    const float* wptr = out + 32768 + b * 2048;
    float ax = 0.f, ay = 0.f, az = 0.f, aw = 0.f;
    int sbase = ss * 128 + sg;
    #pragma unroll 8
    for (int i = 0; i < 32; ++i) {
        int s = sbase + i * 4;
        float wv = wptr[s];                                // wave-uniform -> scalar load
        float4 e = *(const float4*)(enc + ((size_t)b * 2048 + s) * 512 + h);
        ax += wv * e.x; ay += wv * e.y; az += wv * e.z; aw += wv * e.w;
    }
    __shared__ float red[4][64][4];
    red[sg][lane][0] = ax; red[sg][lane][1] = ay; red[sg][lane][2] = az; red[sg][lane][3] = aw;
    __syncthreads();
    if (t < 64) {
        float* dst = out + b * 512 + hc * 256 + t * 4;
        #pragma unroll
        for (int j = 0; j < 4; ++j) {
            float sv = red[0][t][j] + red[1][t][j] + red[2][t][j] + red[3][t][j];
            atomicAdd(dst + j, sv);
        }
    }
}

extern "C" void kernel_launch(void* const* d_in, const int* in_sizes, int n_in,
                              void* d_out, int out_size, void* d_ws, size_t ws_size,
                              hipStream_t stream) {
    const float* dec = (const float*)d_in[0];
    const float* enc = (const float*)d_in[1];
    const float* wq  = (const float*)d_in[2];
    const float* wk  = (const float*)d_in[3];
    const float* v   = (const float*)d_in[4];
    float* out = (float*)d_out;

    unsigned short* wkb = (unsigned short*)d_ws;                 // 512*512*2 = 512 KiB
    float* q = (float*)((char*)d_ws + 512 * 512 * 2);            // 64*512*4  = 128 KiB

    cast_wk_kernel<<<256, 256, 0, stream>>>(wk, wkb);
    q_kernel<<<512, 256, 0, stream>>>(dec, wq, q);
    scores_kernel<<<2048, 256, 0, stream>>>(enc, wkb, q, v, out + 32768);
    softmax_kernel<<<64, 256, 0, stream>>>(out);
    context_kernel<<<2048, 256, 0, stream>>>(enc, out);
}